// Round 10
// baseline (858.762 us; speedup 1.0000x reference)
//
#include <hip/hip_runtime.h>

#define NEG_SLOPE 0.2f
#define PRELU_W 0.1f

__device__ __forceinline__ float d_lrelu(float v){ return fmaxf(v, NEG_SLOPE * v); }
__device__ __forceinline__ float d_prelu(float v){ return fmaxf(v, PRELU_W * v); }

// bf16 helpers (round-to-nearest-even), no header dependency
__device__ __forceinline__ unsigned short f2bf(float f){
  unsigned int u = __builtin_bit_cast(unsigned int, f);
  unsigned int r = (u + 0x7fffu + ((u >> 16) & 1u)) >> 16;
  return (unsigned short)r;
}
__device__ __forceinline__ float bflo(unsigned int u){ return __builtin_bit_cast(float, u << 16); }
__device__ __forceinline__ float bfhi(unsigned int u){ return __builtin_bit_cast(float, u & 0xffff0000u); }

// ============================ CSR build (R7 config) ============================

__global__ void k_zero(int* __restrict__ p, int n){
  int i = blockIdx.x * 256 + threadIdx.x;
  if (i < n) p[i] = 0;
}

// Count degrees for BOTH graphs, 2 edges per thread; atomicAdd's return IS the
// edge's rank within its destination.
__global__ void k_count_rank(const int* __restrict__ eiS, const int* __restrict__ eiK,
                             int* __restrict__ degS, int* __restrict__ degK,
                             int* __restrict__ rankS, int* __restrict__ rankK, int E){
  int e0 = blockIdx.x * 512 + threadIdx.x;
  int e1 = e0 + 256;
  bool v0 = e0 < E, v1 = e1 < E;
  int dS0 = 0, dK0 = 0, dS1 = 0, dK1 = 0;
  if (v0){ dS0 = eiS[E + e0]; dK0 = eiK[E + e0]; }
  if (v1){ dS1 = eiS[E + e1]; dK1 = eiK[E + e1]; }
  if (v0){
    rankS[e0] = atomicAdd(&degS[dS0], 1);
    rankK[e0] = atomicAdd(&degK[dK0], 1);
  }
  if (v1){
    rankS[e1] = atomicAdd(&degS[dS1], 1);
    rankK[e1] = atomicAdd(&degK[dK1], 1);
  }
}

// chunk=1024 per block (256 thr x 4); grid.y selects graph
__global__ void k_scan1(const int* __restrict__ degS, const int* __restrict__ degK,
                        int* __restrict__ bsumS, int* __restrict__ bsumK, int n){
  const int* deg = blockIdx.y ? degK : degS;
  int* bsum = blockIdx.y ? bsumK : bsumS;
  int b = blockIdx.x, t = threadIdx.x;
  int base = b * 1024 + t * 4;
  int s = 0;
  #pragma unroll
  for (int k2 = 0; k2 < 4; ++k2){ int i = base + k2; if (i < n) s += deg[i]; }
  #pragma unroll
  for (int d = 32; d >= 1; d >>= 1) s += __shfl_xor(s, d, 64);
  __shared__ int ws[4];
  int lane = t & 63, wid = t >> 6;
  if (lane == 0) ws[wid] = s;
  __syncthreads();
  if (t == 0) bsum[b] = ws[0] + ws[1] + ws[2] + ws[3];
}

// 2 blocks (one per graph), 128 threads: exclusive-scan bsum (nb <= 128)
__global__ void k_scan2(int* __restrict__ bsumS, int* __restrict__ bsumK, int nb,
                        int* __restrict__ rsS, int* __restrict__ rsK, int n){
  int* bsum = blockIdx.x ? bsumK : bsumS;
  int* rs = blockIdx.x ? rsK : rsS;
  int t = threadIdx.x;
  int v = (t < nb) ? bsum[t] : 0;
  int x = v;
  int lane = t & 63, wid = t >> 6;
  #pragma unroll
  for (int d = 1; d < 64; d <<= 1){ int y = __shfl_up(x, d, 64); if (lane >= d) x += y; }
  __shared__ int wq[2];
  if (lane == 63) wq[wid] = x;
  __syncthreads();
  if (wid == 1) x += wq[0];
  if (t < nb) bsum[t] = x - v;
  if (t == nb - 1) rs[n] = x;
}

__global__ void k_scan3(const int* __restrict__ degS, const int* __restrict__ degK,
                        const int* __restrict__ bsumS, const int* __restrict__ bsumK,
                        int* __restrict__ rsS, int* __restrict__ rsK, int n){
  const int* deg = blockIdx.y ? degK : degS;
  const int* bsum = blockIdx.y ? bsumK : bsumS;
  int* rs = blockIdx.y ? rsK : rsS;
  int b = blockIdx.x, t = threadIdx.x;
  int base = b * 1024 + t * 4;
  int v[4];
  #pragma unroll
  for (int k2 = 0; k2 < 4; ++k2){ int i = base + k2; v[k2] = (i < n) ? deg[i] : 0; }
  int tsum = v[0] + v[1] + v[2] + v[3];
  int x = tsum;
  int lane = t & 63, wid = t >> 6;
  #pragma unroll
  for (int d = 1; d < 64; d <<= 1){ int y = __shfl_up(x, d, 64); if (lane >= d) x += y; }
  __shared__ int ws[4];
  if (lane == 63) ws[wid] = x;
  __syncthreads();
  int woff = 0;
  for (int w = 0; w < wid; ++w) woff += ws[w];
  int run = bsum[b] + woff + (x - tsum);
  #pragma unroll
  for (int k2 = 0; k2 < 4; ++k2){ int i = base + k2; if (i < n) rs[i] = run; run += v[k2]; }
}

// Atomic-free placement: slot = rs[d] + precomputed rank. 2 edges/thread.
__global__ void k_place(const int* __restrict__ eiS, const int* __restrict__ eiK,
                        const int* __restrict__ rsS, const int* __restrict__ rsK,
                        const int* __restrict__ rankS, const int* __restrict__ rankK,
                        int* __restrict__ colS, int* __restrict__ colK, int E){
  int e0 = blockIdx.x * 512 + threadIdx.x;
  int e1 = e0 + 256;
  bool v0 = e0 < E, v1 = e1 < E;
  if (v0){
    int sS = eiS[e0], dS = eiS[E + e0];
    int sK = eiK[e0], dK = eiK[E + e0];
    int rS = rankS[e0], rK = rankK[e0];
    colS[rsS[dS] + rS] = sS;
    colK[rsK[dK] + rK] = sK;
  }
  if (v1){
    int sS = eiS[e1], dS = eiS[E + e1];
    int sK = eiK[e1], dK = eiK[E + e1];
    int rS = rankS[e1], rK = rankK[e1];
    colS[rsS[dS] + rS] = sS;
    colK[rsK[dK] + rK] = sK;
  }
}

// ============================ GAT layer 1 (x is [N,1]) ============================
__global__ void k_gat_l1(const int* __restrict__ rsA, const int* __restrict__ colA,
                         const int* __restrict__ rsB, const int* __restrict__ colB,
                         const float* __restrict__ x,
                         const float* __restrict__ WA, const float* __restrict__ bA,
                         const float* __restrict__ a1A, const float* __restrict__ a2A,
                         const float* __restrict__ WB, const float* __restrict__ bB,
                         const float* __restrict__ a1B, const float* __restrict__ a2B,
                         float* __restrict__ outA, float* __restrict__ outB, int n){
  bool g = (blockIdx.y != 0);
  const int* rs  = g ? rsB  : rsA;
  const int* col = g ? colB : colA;
  const float* W = g ? WB : WA;  const float* bias = g ? bB : bA;
  const float* a1 = g ? a1B : a1A; const float* a2 = g ? a2B : a2A;
  float* outp = g ? outB : outA;

  __shared__ float sp[2];
  int t = threadIdx.x;
  if (t < 32){
    float wk = W[t];
    float q1 = wk * a1[t], q2 = wk * a2[t];
    #pragma unroll
    for (int d = 16; d >= 1; d >>= 1){ q1 += __shfl_xor(q1, d, 32); q2 += __shfl_xor(q2, d, 32); }
    if (t == 0){ sp[0] = q1; sp[1] = q2; }
  }
  __syncthreads();
  float p1 = sp[0], p2 = sp[1];

  int gid = blockIdx.x * 256 + t;
  int node = gid >> 3, l8 = gid & 7;
  if (node >= n) return;
  float a2d = x[node] * p2;
  int beg = rs[node], end = rs[node + 1];
  float denom = 0.f, accx = 0.f;
  #pragma unroll 2
  for (int idx = beg + l8; idx < end; idx += 8){
    float xs = x[col[idx]];
    float w = __expf(d_lrelu(xs * p1 + a2d));
    denom += w;
    accx += w * xs;
  }
  #pragma unroll
  for (int d = 4; d >= 1; d >>= 1){
    denom += __shfl_xor(denom, d, 8);
    accx  += __shfl_xor(accx,  d, 8);
  }
  float r = accx / (denom + 1e-16f);
  float4 Wv = *(const float4*)(W + l8 * 4);
  float4 Bv = *(const float4*)(bias + l8 * 4);
  float4 o;
  o.x = d_prelu(r * Wv.x + Bv.x);
  o.y = d_prelu(r * Wv.y + Bv.y);
  o.z = d_prelu(r * Wv.z + Bv.z);
  o.w = d_prelu(r * Wv.w + Bv.w);
  *(float4*)(outp + (size_t)node * 32 + l8 * 4) = o;
}

// ============================ per-layer linear ============================
__global__ void k_linear(const float* __restrict__ se, const float* __restrict__ sk,
                         const float* __restrict__ WS, const float* __restrict__ WK,
                         const float* __restrict__ a1S, const float* __restrict__ a2S,
                         const float* __restrict__ a1K, const float* __restrict__ a2K,
                         unsigned short* __restrict__ hS, unsigned short* __restrict__ hK,
                         float* __restrict__ oa1S, float* __restrict__ oa2S,
                         float* __restrict__ oa1K, float* __restrict__ oa2K, int n){
  __shared__ float sWS[1024], sWK[1024], sa[128];
  int t = threadIdx.x;
  for (int i = t; i < 1024; i += 256){ sWS[i] = WS[i]; sWK[i] = WK[i]; }
  if (t < 32){ sa[t] = a1S[t]; sa[32 + t] = a2S[t]; sa[64 + t] = a1K[t]; sa[96 + t] = a2K[t]; }
  __syncthreads();
  int gid = blockIdx.x * 256 + t;
  int node = gid >> 5, k = gid & 31;
  if (node >= n) return;
  float c = se[node * 32 + k] + sk[node * 32 + k];
  float hs = 0.f, hk = 0.f;
  #pragma unroll
  for (int m = 0; m < 32; ++m){
    float cm = __shfl(c, m, 32);
    hs += cm * sWS[m * 32 + k];
    hk += cm * sWK[m * 32 + k];
  }
  hS[node * 32 + k] = f2bf(hs);
  hK[node * 32 + k] = f2bf(hk);
  float r1 = hs * sa[k], r2 = hs * sa[32 + k], r3 = hk * sa[64 + k], r4 = hk * sa[96 + k];
  #pragma unroll
  for (int d = 16; d >= 1; d >>= 1){
    r1 += __shfl_xor(r1, d, 32); r2 += __shfl_xor(r2, d, 32);
    r3 += __shfl_xor(r3, d, 32); r4 += __shfl_xor(r4, d, 32);
  }
  if (k == 0){ oa1S[node] = r1; oa2S[node] = r2; oa1K[node] = r3; oa2K[node] = r4; }
}

// ============================ GAT aggregation, two-phase ============================
// Block = 256 thr, 8 consecutive dst nodes -> contiguous col segment.
// Phase 1 (coalesced): thread t loads col[base+t], gathers a1[s], finds its dst
// via 7-compare search in the LDS rs-window, computes w, stashes (s,w) in LDS.
// Phase 2: 2 nodes/wave, 8 edge-groups x 4 k-lanes (uint4); s,w from LDS ->
// the h-row gather is the only global dependent load.
__global__ void k_gat_agg2(const int* __restrict__ rsA, const int* __restrict__ colA,
                           const unsigned short* __restrict__ hA,
                           const float* __restrict__ a1A, const float* __restrict__ a2A,
                           const float* __restrict__ bA, float* __restrict__ outA,
                           const int* __restrict__ rsB, const int* __restrict__ colB,
                           const unsigned short* __restrict__ hB,
                           const float* __restrict__ a1B, const float* __restrict__ a2B,
                           const float* __restrict__ bB, float* __restrict__ outB, int n){
  bool gB = (blockIdx.y != 0);
  const int* rs  = gB ? rsB  : rsA;
  const int* col = gB ? colB : colA;
  const unsigned short* h = gB ? hB : hA;
  const float* a1 = gB ? a1B : a1A;
  const float* a2 = gB ? a2B : a2A;
  const float* bias = gB ? bB : bA;
  float* outp = gB ? outB : outA;

  __shared__ int rsL[9];
  __shared__ int sC[256];
  __shared__ float wC[256];

  int t = threadIdx.x;
  int n0 = blockIdx.x * 8;
  if (t < 9){
    int idx = n0 + t;
    rsL[t] = rs[idx < n ? idx : n];
  }
  __syncthreads();
  int seg0 = rsL[0], segEnd = rsL[8];

  // phase-2 lane decomposition
  int lane = t & 63;
  int half = lane >> 5, l32 = lane & 31;
  int nl = (t >> 6) * 2 + half;            // local node 0..7
  int node = n0 + nl;
  int g = l32 >> 2;                        // 8 edge groups
  int k = (l32 & 3) * 8;                   // 8 bf16 per lane
  int myBeg = rsL[nl], myEnd = rsL[nl + 1];
  int deg = myEnd - myBeg;
  float a2d = (node < n) ? a2[node] : 0.f;

  float acc[8] = {0.f,0.f,0.f,0.f,0.f,0.f,0.f,0.f};
  float dpart = 0.f;

  for (int base = seg0; base < segEnd; base += 256){
    int j = base + t;
    int sv = 0; float wv = 0.f;
    bool val = j < segEnd;
    if (val){
      sv = col[j];
      int dl = 0;
      #pragma unroll
      for (int i = 1; i < 8; ++i) dl += (j >= rsL[i]);
      wv = __expf(d_lrelu(a1[sv] + a2[n0 + dl]));
    }
    __syncthreads();   // previous phase 2 done before overwrite
    if (val){ sC[t] = sv; wC[t] = wv; }
    __syncthreads();
    // phase 2: my node's edges within this chunk
    int lo = (myBeg > base) ? myBeg : base;
    int hi = (myEnd < base + 256) ? myEnd : (base + 256);
    // first ordinal >= lo-myBeg congruent to g mod 8
    int o0 = lo - myBeg;
    int r8 = o0 & 7;
    int ord = o0 + ((g - r8) & 7);
    #pragma unroll 2
    for (; myBeg + ord < hi; ord += 8){
      int li = myBeg + ord - base;
      int s = sC[li];
      float w = wC[li];
      uint4 hv = *(const uint4*)(h + (((size_t)s) << 5) + k);
      dpart += w;
      acc[0] += w * bflo(hv.x); acc[1] += w * bfhi(hv.x);
      acc[2] += w * bflo(hv.y); acc[3] += w * bfhi(hv.y);
      acc[4] += w * bflo(hv.z); acc[5] += w * bfhi(hv.z);
      acc[6] += w * bflo(hv.w); acc[7] += w * bfhi(hv.w);
    }
  }

  #pragma unroll
  for (int m = 4; m <= 16; m <<= 1){
    #pragma unroll
    for (int i = 0; i < 8; ++i) acc[i] += __shfl_xor(acc[i], m, 32);
    dpart += __shfl_xor(dpart, m, 32);
  }
  if (g == 0 && node < n){
    float inv = 1.f / (dpart + 1e-16f);
    float4 b0 = *(const float4*)(bias + k);
    float4 b1 = *(const float4*)(bias + k + 4);
    float4 o0v, o1v;
    o0v.x = d_prelu(acc[0] * inv + b0.x);
    o0v.y = d_prelu(acc[1] * inv + b0.y);
    o0v.z = d_prelu(acc[2] * inv + b0.z);
    o0v.w = d_prelu(acc[3] * inv + b0.w);
    o1v.x = d_prelu(acc[4] * inv + b1.x);
    o1v.y = d_prelu(acc[5] * inv + b1.y);
    o1v.z = d_prelu(acc[6] * inv + b1.z);
    o1v.w = d_prelu(acc[7] * inv + b1.w);
    *(float4*)(outp + (size_t)node * 32 + k) = o0v;
    *(float4*)(outp + (size_t)node * 32 + k + 4) = o1v;
  }
}

// ============================ output head 0 ============================
__global__ void k_head0(const float* __restrict__ se, const float* __restrict__ sk,
                        const float* __restrict__ Wos, const float* __restrict__ bos,
                        const float* __restrict__ Wok, const float* __restrict__ bok,
                        unsigned short* __restrict__ comb, float* __restrict__ outp, int n){
  int gid = blockIdx.x * 256 + threadIdx.x;
  int node = gid >> 6, k = gid & 63;
  if (node >= n) return;
  float cv = (k < 32) ? se[node * 32 + k] : sk[node * 32 + (k - 32)];
  comb[(size_t)node * 64 + k] = f2bf(cv);
  float s0 = cv * Wos[k * 2], s1 = cv * Wos[k * 2 + 1];
  float q0 = cv * Wok[k * 2], q1 = cv * Wok[k * 2 + 1];
  #pragma unroll
  for (int d = 32; d >= 1; d >>= 1){
    s0 += __shfl_xor(s0, d, 64); s1 += __shfl_xor(s1, d, 64);
    q0 += __shfl_xor(q0, d, 64); q1 += __shfl_xor(q1, d, 64);
  }
  if (k == 0){
    float f0 = (fmaxf(s0 + bos[0], 0.f) + fmaxf(q0 + bok[0], 0.f)) * 0.5f;
    float f1 = (fmaxf(s1 + bos[1], 0.f) + fmaxf(q1 + bok[1], 0.f)) * 0.5f;
    outp[node * 4 + 0] = f0;
    outp[node * 4 + 1] = f1;
  }
}

// ============================ output head 1, two-phase ============================
// Block = 256 thr, 4 consecutive nodes (1 wave/node). Per graph: phase 1 loads
// (col, x[s]) coalesced into LDS; phase 2 gathers comb rows (only dependent load).
__global__ void k_head1b(const int* __restrict__ rsS, const int* __restrict__ colS,
                         const int* __restrict__ rsK, const int* __restrict__ colK,
                         const unsigned short* __restrict__ comb, const float* __restrict__ x,
                         const float* __restrict__ Wd1, const float* __restrict__ bd1,
                         float* __restrict__ outp, int n){
  __shared__ int rsL[5];
  __shared__ int sC[256];
  __shared__ float xC[256];

  int t = threadIdx.x;
  int n0 = blockIdx.x * 4;
  int lane = t & 63;
  int nl = t >> 6;
  int node = n0 + nl;
  int g8 = lane >> 3, k8 = (lane & 7) * 8;

  float aS[8] = {0.f,0.f,0.f,0.f,0.f,0.f,0.f,0.f};
  float aK[8] = {0.f,0.f,0.f,0.f,0.f,0.f,0.f,0.f};

  for (int gr = 0; gr < 2; ++gr){
    const int* rs  = gr ? rsK : rsS;
    const int* col = gr ? colK : colS;
    float* acc = gr ? aK : aS;
    __syncthreads();
    if (t < 5){
      int idx = n0 + t;
      rsL[t] = rs[idx < n ? idx : n];
    }
    __syncthreads();
    int seg0 = rsL[0], segEnd = rsL[4];
    int myBeg = rsL[nl], myEnd = rsL[nl + 1];
    for (int base = seg0; base < segEnd; base += 256){
      int j = base + t;
      int sv = 0; float xv = 0.f;
      bool val = j < segEnd;
      if (val){ sv = col[j]; xv = x[sv]; }
      __syncthreads();
      if (val){ sC[t] = sv; xC[t] = xv; }
      __syncthreads();
      int lo = (myBeg > base) ? myBeg : base;
      int hi = (myEnd < base + 256) ? myEnd : (base + 256);
      int o0 = lo - myBeg;
      int r8 = o0 & 7;
      int ord = o0 + ((g8 - r8) & 7);
      #pragma unroll 2
      for (; myBeg + ord < hi; ord += 8){
        int li = myBeg + ord - base;
        int s = sC[li];
        float xs = xC[li];
        uint4 cv = *(const uint4*)(comb + (((size_t)s) << 6) + k8);
        acc[0] += xs * bflo(cv.x); acc[1] += xs * bfhi(cv.x);
        acc[2] += xs * bflo(cv.y); acc[3] += xs * bfhi(cv.y);
        acc[4] += xs * bflo(cv.z); acc[5] += xs * bfhi(cv.z);
        acc[6] += xs * bflo(cv.w); acc[7] += xs * bfhi(cv.w);
      }
    }
  }

  #pragma unroll
  for (int m = 8; m <= 32; m <<= 1){
    #pragma unroll
    for (int i = 0; i < 8; ++i){
      aS[i] += __shfl_xor(aS[i], m, 64);
      aK[i] += __shfl_xor(aK[i], m, 64);
    }
  }
  if (node < n){
    uint4 cs = *(const uint4*)(comb + (((size_t)node) << 6) + k8);
    float c[8] = { bflo(cs.x), bfhi(cs.x), bflo(cs.y), bfhi(cs.y),
                   bflo(cs.z), bfhi(cs.z), bflo(cs.w), bfhi(cs.w) };
    float r0 = 0.f, r1 = 0.f;
    #pragma unroll
    for (int i = 0; i < 8; ++i){
      float cd = c[i] * 0.5f;
      float tv = fmaxf(aS[i] + cd, 0.f) + fmaxf(aK[i] + cd, 0.f);
      float2 w = *(const float2*)(Wd1 + (k8 + i) * 2);
      r0 += tv * w.x;
      r1 += tv * w.y;
    }
    #pragma unroll
    for (int m = 1; m <= 4; m <<= 1){
      r0 += __shfl_xor(r0, m, 64);
      r1 += __shfl_xor(r1, m, 64);
    }
    if (lane == 0){
      outp[(size_t)node * 4 + 2] = fmaxf(r0 + bd1[0], 0.f);
      outp[(size_t)node * 4 + 3] = fmaxf(r1 + bd1[1], 0.f);
    }
  }
}

// ============================ launch ============================

extern "C" void kernel_launch(void* const* d_in, const int* in_sizes, int n_in,
                              void* d_out, int out_size, void* d_ws, size_t ws_size,
                              hipStream_t stream) {
  const float* x      = (const float*)d_in[0];
  const int*   eiS    = (const int*)d_in[1];
  const int*   eiK    = (const int*)d_in[2];
  const float* W_in_src = (const float*)d_in[3];
  const float* b_in_src = (const float*)d_in[4];
  const float* a1_in_src= (const float*)d_in[5];
  const float* a2_in_src= (const float*)d_in[6];
  const float* W_in_snk = (const float*)d_in[7];
  const float* b_in_snk = (const float*)d_in[8];
  const float* a1_in_snk= (const float*)d_in[9];
  const float* a2_in_snk= (const float*)d_in[10];
  const float* W_src  = (const float*)d_in[11];
  const float* b_src  = (const float*)d_in[12];
  const float* a1_src = (const float*)d_in[13];
  const float* a2_src = (const float*)d_in[14];
  const float* W_snk  = (const float*)d_in[15];
  const float* b_snk  = (const float*)d_in[16];
  const float* a1_snk = (const float*)d_in[17];
  const float* a2_snk = (const float*)d_in[18];
  const float* W_o_src= (const float*)d_in[19];
  const float* b_o_src= (const float*)d_in[20];
  const float* W_o_snk= (const float*)d_in[21];
  const float* b_o_snk= (const float*)d_in[22];
  const float* W_d1   = (const float*)d_in[23];
  const float* b_d1   = (const float*)d_in[24];
  float* outp = (float*)d_out;

  const int N = in_sizes[0];       // 100000
  const int E = in_sizes[1] / 2;   // 1600000
  const int L = 5;

  // ---- workspace layout: floats, ints, then bf16 ----
  float* f = (float*)d_ws;
  float* seA = f;  f += (size_t)N * 32;
  float* skA = f;  f += (size_t)N * 32;
  float* a1Sv = f; f += N;
  float* a2Sv = f; f += N;
  float* a1Kv = f; f += N;
  float* a2Kv = f; f += N;
  int* ip = (int*)f;
  int* rsS    = ip; ip += N + 4;   // padded to keep 16B alignment downstream
  int* rsK    = ip; ip += N + 4;
  int* colS   = ip; ip += E;
  int* colK   = ip; ip += E;
  int* degS   = ip; ip += N;   // degS/degK adjacent -> single zero pass
  int* degK   = ip; ip += N;
  int* bsumS  = ip; ip += 256;
  int* bsumK  = ip; ip += 256;
  unsigned short* us = (unsigned short*)ip;
  unsigned short* hS   = us; us += (size_t)N * 32;
  unsigned short* hK   = us; us += (size_t)N * 32;
  unsigned short* comb = us; us += (size_t)N * 64;
  // rank arrays alias hS/hK: dead before k_linear first writes them
  int* rankS = (int*)hS;
  int* rankK = (int*)hK;

  const int TB = 256;
  int gE2   = (E + 511) / 512;
  int gN32  = (N * 32 + TB - 1) / TB;
  int gN64  = (N * 64 + TB - 1) / TB;
  int gN8   = (N * 8 + TB - 1) / TB;
  int gNode8 = (N + 7) / 8;
  int gNode4 = (N + 3) / 4;
  int nb    = (N + 1023) / 1024;

  // ---- CSR build ----
  hipLaunchKernelGGL(k_zero,  dim3((2 * N + TB - 1) / TB), dim3(TB), 0, stream, degS, 2 * N);
  hipLaunchKernelGGL(k_count_rank, dim3(gE2), dim3(TB), 0, stream,
                     eiS, eiK, degS, degK, rankS, rankK, E);
  hipLaunchKernelGGL(k_scan1, dim3(nb, 2), dim3(TB), 0, stream, degS, degK, bsumS, bsumK, N);
  hipLaunchKernelGGL(k_scan2, dim3(2), dim3(128), 0, stream, bsumS, bsumK, nb, rsS, rsK, N);
  hipLaunchKernelGGL(k_scan3, dim3(nb, 2), dim3(TB), 0, stream,
                     degS, degK, bsumS, bsumK, rsS, rsK, N);
  hipLaunchKernelGGL(k_place, dim3(gE2), dim3(TB), 0, stream,
                     eiS, eiK, rsS, rsK, rankS, rankK, colS, colK, E);

  // ---- layer 1 (input), both graphs fused via grid.y ----
  hipLaunchKernelGGL(k_gat_l1, dim3(gN8, 2), dim3(TB), 0, stream,
                     rsS, colS, rsK, colK, x,
                     W_in_src, b_in_src, a1_in_src, a2_in_src,
                     W_in_snk, b_in_snk, a1_in_snk, a2_in_snk,
                     seA, skA, N);

  // ---- layers 2..L ----
  for (int i = 0; i < L - 1; ++i){
    hipLaunchKernelGGL(k_linear, dim3(gN32), dim3(TB), 0, stream,
                       seA, skA, W_src + (size_t)i * 1024, W_snk + (size_t)i * 1024,
                       a1_src + i * 32, a2_src + i * 32, a1_snk + i * 32, a2_snk + i * 32,
                       hS, hK, a1Sv, a2Sv, a1Kv, a2Kv, N);
    hipLaunchKernelGGL(k_gat_agg2, dim3(gNode8, 2), dim3(TB), 0, stream,
                       rsS, colS, hS, a1Sv, a2Sv, b_src + i * 32, seA,
                       rsK, colK, hK, a1Kv, a2Kv, b_snk + i * 32, skA, N);
  }

  // ---- heads ----
  hipLaunchKernelGGL(k_head0, dim3(gN64), dim3(TB), 0, stream,
                     seA, skA, W_o_src, b_o_src, W_o_snk, b_o_snk, comb, outp, N);
  hipLaunchKernelGGL(k_head1b, dim3(gNode4), dim3(TB), 0, stream,
                     rsS, colS, rsK, colK, comb, x, W_d1, b_d1, outp, N);
}

// Round 11
// 857.044 us; speedup vs baseline: 1.0020x; 1.0020x over previous
//
#include <hip/hip_runtime.h>

#define NEG_SLOPE 0.2f
#define PRELU_W 0.1f

__device__ __forceinline__ float d_lrelu(float v){ return fmaxf(v, NEG_SLOPE * v); }
__device__ __forceinline__ float d_prelu(float v){ return fmaxf(v, PRELU_W * v); }

// bf16 helpers (round-to-nearest-even), no header dependency
__device__ __forceinline__ unsigned short f2bf(float f){
  unsigned int u = __builtin_bit_cast(unsigned int, f);
  unsigned int r = (u + 0x7fffu + ((u >> 16) & 1u)) >> 16;
  return (unsigned short)r;
}
__device__ __forceinline__ float bflo(unsigned int u){ return __builtin_bit_cast(float, u << 16); }
__device__ __forceinline__ float bfhi(unsigned int u){ return __builtin_bit_cast(float, u & 0xffff0000u); }

// ============================ CSR build ============================

__global__ void k_zero(int* __restrict__ p, int n){
  int i = blockIdx.x * 256 + threadIdx.x;
  if (i < n) p[i] = 0;
}

// Count degrees for BOTH graphs, 2 edges per thread (4 independent atomics in
// flight); atomicAdd's return IS the edge's rank within its destination.
__global__ void k_count_rank(const int* __restrict__ eiS, const int* __restrict__ eiK,
                             int* __restrict__ degS, int* __restrict__ degK,
                             int* __restrict__ rankS, int* __restrict__ rankK, int E){
  int e0 = blockIdx.x * 512 + threadIdx.x;
  int e1 = e0 + 256;
  bool v0 = e0 < E, v1 = e1 < E;
  int dS0 = 0, dK0 = 0, dS1 = 0, dK1 = 0;
  if (v0){ dS0 = eiS[E + e0]; dK0 = eiK[E + e0]; }
  if (v1){ dS1 = eiS[E + e1]; dK1 = eiK[E + e1]; }
  if (v0){
    rankS[e0] = atomicAdd(&degS[dS0], 1);
    rankK[e0] = atomicAdd(&degK[dK0], 1);
  }
  if (v1){
    rankS[e1] = atomicAdd(&degS[dS1], 1);
    rankK[e1] = atomicAdd(&degK[dK1], 1);
  }
}

// chunk=1024 per block (256 thr x 4); grid.y selects graph
__global__ void k_scan1(const int* __restrict__ degS, const int* __restrict__ degK,
                        int* __restrict__ bsumS, int* __restrict__ bsumK, int n){
  const int* deg = blockIdx.y ? degK : degS;
  int* bsum = blockIdx.y ? bsumK : bsumS;
  int b = blockIdx.x, t = threadIdx.x;
  int base = b * 1024 + t * 4;
  int s = 0;
  #pragma unroll
  for (int k2 = 0; k2 < 4; ++k2){ int i = base + k2; if (i < n) s += deg[i]; }
  #pragma unroll
  for (int d = 32; d >= 1; d >>= 1) s += __shfl_xor(s, d, 64);
  __shared__ int ws[4];
  int lane = t & 63, wid = t >> 6;
  if (lane == 0) ws[wid] = s;
  __syncthreads();
  if (t == 0) bsum[b] = ws[0] + ws[1] + ws[2] + ws[3];
}

// 2 blocks (one per graph), 128 threads: exclusive-scan bsum (nb <= 128)
__global__ void k_scan2(int* __restrict__ bsumS, int* __restrict__ bsumK, int nb,
                        int* __restrict__ rsS, int* __restrict__ rsK, int n){
  int* bsum = blockIdx.x ? bsumK : bsumS;
  int* rs = blockIdx.x ? rsK : rsS;
  int t = threadIdx.x;
  int v = (t < nb) ? bsum[t] : 0;
  int x = v;
  int lane = t & 63, wid = t >> 6;
  #pragma unroll
  for (int d = 1; d < 64; d <<= 1){ int y = __shfl_up(x, d, 64); if (lane >= d) x += y; }
  __shared__ int wq[2];
  if (lane == 63) wq[wid] = x;
  __syncthreads();
  if (wid == 1) x += wq[0];
  if (t < nb) bsum[t] = x - v;
  if (t == nb - 1) rs[n] = x;
}

__global__ void k_scan3(const int* __restrict__ degS, const int* __restrict__ degK,
                        const int* __restrict__ bsumS, const int* __restrict__ bsumK,
                        int* __restrict__ rsS, int* __restrict__ rsK, int n){
  const int* deg = blockIdx.y ? degK : degS;
  const int* bsum = blockIdx.y ? bsumK : bsumS;
  int* rs = blockIdx.y ? rsK : rsS;
  int b = blockIdx.x, t = threadIdx.x;
  int base = b * 1024 + t * 4;
  int v[4];
  #pragma unroll
  for (int k2 = 0; k2 < 4; ++k2){ int i = base + k2; v[k2] = (i < n) ? deg[i] : 0; }
  int tsum = v[0] + v[1] + v[2] + v[3];
  int x = tsum;
  int lane = t & 63, wid = t >> 6;
  #pragma unroll
  for (int d = 1; d < 64; d <<= 1){ int y = __shfl_up(x, d, 64); if (lane >= d) x += y; }
  __shared__ int ws[4];
  if (lane == 63) ws[wid] = x;
  __syncthreads();
  int woff = 0;
  for (int w = 0; w < wid; ++w) woff += ws[w];
  int run = bsum[b] + woff + (x - tsum);
  #pragma unroll
  for (int k2 = 0; k2 < 4; ++k2){ int i = base + k2; if (i < n) rs[i] = run; run += v[k2]; }
}

// Atomic-free placement: slot = rs[d] + precomputed rank. 2 edges/thread.
__global__ void k_place(const int* __restrict__ eiS, const int* __restrict__ eiK,
                        const int* __restrict__ rsS, const int* __restrict__ rsK,
                        const int* __restrict__ rankS, const int* __restrict__ rankK,
                        int* __restrict__ colS, int* __restrict__ colK, int E){
  int e0 = blockIdx.x * 512 + threadIdx.x;
  int e1 = e0 + 256;
  bool v0 = e0 < E, v1 = e1 < E;
  if (v0){
    int sS = eiS[e0], dS = eiS[E + e0];
    int sK = eiK[e0], dK = eiK[E + e0];
    int rS = rankS[e0], rK = rankK[e0];
    colS[rsS[dS] + rS] = sS;
    colK[rsK[dK] + rK] = sK;
  }
  if (v1){
    int sS = eiS[e1], dS = eiS[E + e1];
    int sK = eiK[e1], dK = eiK[E + e1];
    int rS = rankS[e1], rK = rankK[e1];
    colS[rsS[dS] + rS] = sS;
    colK[rsK[dK] + rK] = sK;
  }
}

// ============================ GAT layer 1 (x is [N,1]) ============================
// 8 lanes per node; p1/p2 computed once per block; float4 output writes.
__global__ void k_gat_l1(const int* __restrict__ rsA, const int* __restrict__ colA,
                         const int* __restrict__ rsB, const int* __restrict__ colB,
                         const float* __restrict__ x,
                         const float* __restrict__ WA, const float* __restrict__ bA,
                         const float* __restrict__ a1A, const float* __restrict__ a2A,
                         const float* __restrict__ WB, const float* __restrict__ bB,
                         const float* __restrict__ a1B, const float* __restrict__ a2B,
                         float* __restrict__ outA, float* __restrict__ outB, int n){
  bool g = (blockIdx.y != 0);
  const int* rs  = g ? rsB  : rsA;
  const int* col = g ? colB : colA;
  const float* W = g ? WB : WA;  const float* bias = g ? bB : bA;
  const float* a1 = g ? a1B : a1A; const float* a2 = g ? a2B : a2A;
  float* outp = g ? outB : outA;

  __shared__ float sp[2];
  int t = threadIdx.x;
  if (t < 32){
    float wk = W[t];
    float q1 = wk * a1[t], q2 = wk * a2[t];
    #pragma unroll
    for (int d = 16; d >= 1; d >>= 1){ q1 += __shfl_xor(q1, d, 32); q2 += __shfl_xor(q2, d, 32); }
    if (t == 0){ sp[0] = q1; sp[1] = q2; }
  }
  __syncthreads();
  float p1 = sp[0], p2 = sp[1];

  int gid = blockIdx.x * 256 + t;
  int node = gid >> 3, l8 = gid & 7;
  if (node >= n) return;
  float a2d = x[node] * p2;
  int beg = rs[node], end = rs[node + 1];
  float denom = 0.f, accx = 0.f;
  #pragma unroll 2
  for (int idx = beg + l8; idx < end; idx += 8){
    float xs = x[col[idx]];
    float w = __expf(d_lrelu(xs * p1 + a2d));
    denom += w;
    accx += w * xs;
  }
  #pragma unroll
  for (int d = 4; d >= 1; d >>= 1){
    denom += __shfl_xor(denom, d, 8);
    accx  += __shfl_xor(accx,  d, 8);
  }
  float r = accx / (denom + 1e-16f);
  float4 Wv = *(const float4*)(W + l8 * 4);
  float4 Bv = *(const float4*)(bias + l8 * 4);
  float4 o;
  o.x = d_prelu(r * Wv.x + Bv.x);
  o.y = d_prelu(r * Wv.y + Bv.y);
  o.z = d_prelu(r * Wv.z + Bv.z);
  o.w = d_prelu(r * Wv.w + Bv.w);
  *(float4*)(outp + (size_t)node * 32 + l8 * 4) = o;
}

// ============================ per-layer linear ============================
__global__ void k_linear(const float* __restrict__ se, const float* __restrict__ sk,
                         const float* __restrict__ WS, const float* __restrict__ WK,
                         const float* __restrict__ a1S, const float* __restrict__ a2S,
                         const float* __restrict__ a1K, const float* __restrict__ a2K,
                         unsigned short* __restrict__ hS, unsigned short* __restrict__ hK,
                         float* __restrict__ oa1S, float* __restrict__ oa2S,
                         float* __restrict__ oa1K, float* __restrict__ oa2K, int n){
  __shared__ float sWS[1024], sWK[1024], sa[128];
  int t = threadIdx.x;
  for (int i = t; i < 1024; i += 256){ sWS[i] = WS[i]; sWK[i] = WK[i]; }
  if (t < 32){ sa[t] = a1S[t]; sa[32 + t] = a2S[t]; sa[64 + t] = a1K[t]; sa[96 + t] = a2K[t]; }
  __syncthreads();
  int gid = blockIdx.x * 256 + t;
  int node = gid >> 5, k = gid & 31;
  if (node >= n) return;
  float c = se[node * 32 + k] + sk[node * 32 + k];
  float hs = 0.f, hk = 0.f;
  #pragma unroll
  for (int m = 0; m < 32; ++m){
    float cm = __shfl(c, m, 32);
    hs += cm * sWS[m * 32 + k];
    hk += cm * sWK[m * 32 + k];
  }
  hS[node * 32 + k] = f2bf(hs);
  hK[node * 32 + k] = f2bf(hk);
  float r1 = hs * sa[k], r2 = hs * sa[32 + k], r3 = hk * sa[64 + k], r4 = hk * sa[96 + k];
  #pragma unroll
  for (int d = 16; d >= 1; d >>= 1){
    r1 += __shfl_xor(r1, d, 32); r2 += __shfl_xor(r2, d, 32);
    r3 += __shfl_xor(r3, d, 32); r4 += __shfl_xor(r4, d, 32);
  }
  if (k == 0){ oa1S[node] = r1; oa2S[node] = r2; oa1K[node] = r3; oa2K[node] = r4; }
}

// ============================ generic GAT aggregation ============================
// 2 nodes per wave: per node 8 edge-groups x 4 k-lanes (uint4 = 8 bf16/lane).
// 16 concurrent edge streams per wave; reductions stay within 32-lane halves.
__global__ void k_gat_agg(const int* __restrict__ rsA, const int* __restrict__ colA,
                          const unsigned short* __restrict__ hA,
                          const float* __restrict__ a1A, const float* __restrict__ a2A,
                          const float* __restrict__ bA, float* __restrict__ outA,
                          const int* __restrict__ rsB, const int* __restrict__ colB,
                          const unsigned short* __restrict__ hB,
                          const float* __restrict__ a1B, const float* __restrict__ a2B,
                          const float* __restrict__ bB, float* __restrict__ outB, int n){
  bool g2 = (blockIdx.y != 0);
  const int* rs  = g2 ? rsB  : rsA;
  const int* col = g2 ? colB : colA;
  const unsigned short* h = g2 ? hB : hA;
  const float* a1 = g2 ? a1B : a1A;
  const float* a2 = g2 ? a2B : a2A;
  const float* bias = g2 ? bB : bA;
  float* outp = g2 ? outB : outA;

  int t = threadIdx.x;
  int lane = t & 63;
  int half = lane >> 5, l32 = lane & 31;
  int node = blockIdx.x * 8 + (t >> 6) * 2 + half;
  if (node >= n) return;
  int g = l32 >> 2;          // 8 edge groups
  int k = (l32 & 3) * 8;     // element offset: 8 bf16 per lane
  float a2d = a2[node];
  int beg = rs[node], end = rs[node + 1];
  float acc[8] = {0.f,0.f,0.f,0.f,0.f,0.f,0.f,0.f};
  float dpart = 0.f;
  #pragma unroll 2
  for (int idx = beg + g; idx < end; idx += 8){
    int s = col[idx];
    float w = __expf(d_lrelu(a1[s] + a2d));
    uint4 hv = *(const uint4*)(h + (((size_t)s) << 5) + k);
    dpart += w;
    acc[0] += w * bflo(hv.x); acc[1] += w * bfhi(hv.x);
    acc[2] += w * bflo(hv.y); acc[3] += w * bfhi(hv.y);
    acc[4] += w * bflo(hv.z); acc[5] += w * bfhi(hv.z);
    acc[6] += w * bflo(hv.w); acc[7] += w * bfhi(hv.w);
  }
  #pragma unroll
  for (int m = 4; m <= 16; m <<= 1){
    #pragma unroll
    for (int i = 0; i < 8; ++i) acc[i] += __shfl_xor(acc[i], m, 32);
    dpart += __shfl_xor(dpart, m, 32);
  }
  if (g == 0){
    float inv = 1.f / (dpart + 1e-16f);
    float4 b0 = *(const float4*)(bias + k);
    float4 b1 = *(const float4*)(bias + k + 4);
    float4 o0, o1;
    o0.x = d_prelu(acc[0] * inv + b0.x);
    o0.y = d_prelu(acc[1] * inv + b0.y);
    o0.z = d_prelu(acc[2] * inv + b0.z);
    o0.w = d_prelu(acc[3] * inv + b0.w);
    o1.x = d_prelu(acc[4] * inv + b1.x);
    o1.y = d_prelu(acc[5] * inv + b1.y);
    o1.z = d_prelu(acc[6] * inv + b1.z);
    o1.w = d_prelu(acc[7] * inv + b1.w);
    *(float4*)(outp + (size_t)node * 32 + k) = o0;
    *(float4*)(outp + (size_t)node * 32 + k + 4) = o1;
  }
}

// ============================ output head 0 ============================
__global__ void k_head0(const float* __restrict__ se, const float* __restrict__ sk,
                        const float* __restrict__ Wos, const float* __restrict__ bos,
                        const float* __restrict__ Wok, const float* __restrict__ bok,
                        unsigned short* __restrict__ comb, float* __restrict__ outp, int n){
  int gid = blockIdx.x * 256 + threadIdx.x;
  int node = gid >> 6, k = gid & 63;
  if (node >= n) return;
  float cv = (k < 32) ? se[node * 32 + k] : sk[node * 32 + (k - 32)];
  comb[(size_t)node * 64 + k] = f2bf(cv);
  float s0 = cv * Wos[k * 2], s1 = cv * Wos[k * 2 + 1];
  float q0 = cv * Wok[k * 2], q1 = cv * Wok[k * 2 + 1];
  #pragma unroll
  for (int d = 32; d >= 1; d >>= 1){
    s0 += __shfl_xor(s0, d, 64); s1 += __shfl_xor(s1, d, 64);
    q0 += __shfl_xor(q0, d, 64); q1 += __shfl_xor(q1, d, 64);
  }
  if (k == 0){
    float f0 = (fmaxf(s0 + bos[0], 0.f) + fmaxf(q0 + bok[0], 0.f)) * 0.5f;
    float f1 = (fmaxf(s1 + bos[1], 0.f) + fmaxf(q1 + bok[1], 0.f)) * 0.5f;
    outp[node * 4 + 0] = f0;
    outp[node * 4 + 1] = f1;
  }
}

// ============================ output head 1 (edge_neighbor) ============================
// One wave per node: 8 edge-groups x 8 k-lanes (uint4 = 8 bf16/lane, 128B row).
__global__ void k_head1(const int* __restrict__ rsS, const int* __restrict__ colS,
                        const int* __restrict__ rsK, const int* __restrict__ colK,
                        const unsigned short* __restrict__ comb, const float* __restrict__ x,
                        const float* __restrict__ Wd1, const float* __restrict__ bd1,
                        float* __restrict__ outp, int n){
  int lane = threadIdx.x & 63;
  int node = blockIdx.x * 4 + (threadIdx.x >> 6);
  if (node >= n) return;
  int g8 = lane >> 3, k8 = (lane & 7) * 8;
  float aS[8] = {0.f,0.f,0.f,0.f,0.f,0.f,0.f,0.f};
  float aK[8] = {0.f,0.f,0.f,0.f,0.f,0.f,0.f,0.f};
  {
    int beg = rsS[node], end = rsS[node + 1];
    #pragma unroll 2
    for (int idx = beg + g8; idx < end; idx += 8){
      int s = colS[idx];
      float xs = x[s];
      uint4 cv = *(const uint4*)(comb + (((size_t)s) << 6) + k8);
      aS[0] += xs * bflo(cv.x); aS[1] += xs * bfhi(cv.x);
      aS[2] += xs * bflo(cv.y); aS[3] += xs * bfhi(cv.y);
      aS[4] += xs * bflo(cv.z); aS[5] += xs * bfhi(cv.z);
      aS[6] += xs * bflo(cv.w); aS[7] += xs * bfhi(cv.w);
    }
  }
  {
    int beg = rsK[node], end = rsK[node + 1];
    #pragma unroll 2
    for (int idx = beg + g8; idx < end; idx += 8){
      int s = colK[idx];
      float xs = x[s];
      uint4 cv = *(const uint4*)(comb + (((size_t)s) << 6) + k8);
      aK[0] += xs * bflo(cv.x); aK[1] += xs * bfhi(cv.x);
      aK[2] += xs * bflo(cv.y); aK[3] += xs * bfhi(cv.y);
      aK[4] += xs * bflo(cv.z); aK[5] += xs * bfhi(cv.z);
      aK[6] += xs * bflo(cv.w); aK[7] += xs * bfhi(cv.w);
    }
  }
  #pragma unroll
  for (int m = 8; m <= 32; m <<= 1){
    #pragma unroll
    for (int i = 0; i < 8; ++i){
      aS[i] += __shfl_xor(aS[i], m, 64);
      aK[i] += __shfl_xor(aK[i], m, 64);
    }
  }
  // lanes 0..7 (g8==0) hold full sums for their k8 slice
  uint4 cs = *(const uint4*)(comb + (((size_t)node) << 6) + k8);
  float c[8] = { bflo(cs.x), bfhi(cs.x), bflo(cs.y), bfhi(cs.y),
                 bflo(cs.z), bfhi(cs.z), bflo(cs.w), bfhi(cs.w) };
  float r0 = 0.f, r1 = 0.f;
  #pragma unroll
  for (int i = 0; i < 8; ++i){
    float cd = c[i] * 0.5f;
    float tv = fmaxf(aS[i] + cd, 0.f) + fmaxf(aK[i] + cd, 0.f);
    float2 w = *(const float2*)(Wd1 + (k8 + i) * 2);
    r0 += tv * w.x;
    r1 += tv * w.y;
  }
  #pragma unroll
  for (int m = 1; m <= 4; m <<= 1){
    r0 += __shfl_xor(r0, m, 64);
    r1 += __shfl_xor(r1, m, 64);
  }
  if (lane == 0){
    outp[(size_t)node * 4 + 2] = fmaxf(r0 + bd1[0], 0.f);
    outp[(size_t)node * 4 + 3] = fmaxf(r1 + bd1[1], 0.f);
  }
}

// ============================ launch ============================

extern "C" void kernel_launch(void* const* d_in, const int* in_sizes, int n_in,
                              void* d_out, int out_size, void* d_ws, size_t ws_size,
                              hipStream_t stream) {
  const float* x      = (const float*)d_in[0];
  const int*   eiS    = (const int*)d_in[1];
  const int*   eiK    = (const int*)d_in[2];
  const float* W_in_src = (const float*)d_in[3];
  const float* b_in_src = (const float*)d_in[4];
  const float* a1_in_src= (const float*)d_in[5];
  const float* a2_in_src= (const float*)d_in[6];
  const float* W_in_snk = (const float*)d_in[7];
  const float* b_in_snk = (const float*)d_in[8];
  const float* a1_in_snk= (const float*)d_in[9];
  const float* a2_in_snk= (const float*)d_in[10];
  const float* W_src  = (const float*)d_in[11];
  const float* b_src  = (const float*)d_in[12];
  const float* a1_src = (const float*)d_in[13];
  const float* a2_src = (const float*)d_in[14];
  const float* W_snk  = (const float*)d_in[15];
  const float* b_snk  = (const float*)d_in[16];
  const float* a1_snk = (const float*)d_in[17];
  const float* a2_snk = (const float*)d_in[18];
  const float* W_o_src= (const float*)d_in[19];
  const float* b_o_src= (const float*)d_in[20];
  const float* W_o_snk= (const float*)d_in[21];
  const float* b_o_snk= (const float*)d_in[22];
  const float* W_d1   = (const float*)d_in[23];
  const float* b_d1   = (const float*)d_in[24];
  float* outp = (float*)d_out;

  const int N = in_sizes[0];       // 100000
  const int E = in_sizes[1] / 2;   // 1600000
  const int L = 5;

  // ---- workspace layout: floats, ints, then bf16 ----
  float* f = (float*)d_ws;
  float* seA = f;  f += (size_t)N * 32;
  float* skA = f;  f += (size_t)N * 32;
  float* a1Sv = f; f += N;
  float* a2Sv = f; f += N;
  float* a1Kv = f; f += N;
  float* a2Kv = f; f += N;
  int* ip = (int*)f;
  int* rsS    = ip; ip += N + 4;   // padded to keep 16B alignment downstream
  int* rsK    = ip; ip += N + 4;
  int* colS   = ip; ip += E;
  int* colK   = ip; ip += E;
  int* degS   = ip; ip += N;   // degS/degK adjacent -> single zero pass
  int* degK   = ip; ip += N;
  int* bsumS  = ip; ip += 256;
  int* bsumK  = ip; ip += 256;
  unsigned short* us = (unsigned short*)ip;
  unsigned short* hS   = us; us += (size_t)N * 32;
  unsigned short* hK   = us; us += (size_t)N * 32;
  unsigned short* comb = us; us += (size_t)N * 64;
  // rank arrays alias hS/hK: dead before k_linear first writes them
  int* rankS = (int*)hS;
  int* rankK = (int*)hK;

  const int TB = 256;
  int gE2   = (E + 511) / 512;
  int gN32  = (N * 32 + TB - 1) / TB;
  int gN64  = (N * 64 + TB - 1) / TB;
  int gN8   = (N * 8 + TB - 1) / TB;
  int gNode4 = (N + 3) / 4;
  int gNode8 = (N + 7) / 8;
  int nb    = (N + 1023) / 1024;

  // ---- CSR build (both graphs fused) ----
  hipLaunchKernelGGL(k_zero,  dim3((2 * N + TB - 1) / TB), dim3(TB), 0, stream, degS, 2 * N);
  hipLaunchKernelGGL(k_count_rank, dim3(gE2), dim3(TB), 0, stream,
                     eiS, eiK, degS, degK, rankS, rankK, E);
  hipLaunchKernelGGL(k_scan1, dim3(nb, 2), dim3(TB), 0, stream, degS, degK, bsumS, bsumK, N);
  hipLaunchKernelGGL(k_scan2, dim3(2), dim3(128), 0, stream, bsumS, bsumK, nb, rsS, rsK, N);
  hipLaunchKernelGGL(k_scan3, dim3(nb, 2), dim3(TB), 0, stream,
                     degS, degK, bsumS, bsumK, rsS, rsK, N);
  hipLaunchKernelGGL(k_place, dim3(gE2), dim3(TB), 0, stream,
                     eiS, eiK, rsS, rsK, rankS, rankK, colS, colK, E);

  // ---- layer 1 (input), both graphs fused via grid.y ----
  hipLaunchKernelGGL(k_gat_l1, dim3(gN8, 2), dim3(TB), 0, stream,
                     rsS, colS, rsK, colK, x,
                     W_in_src, b_in_src, a1_in_src, a2_in_src,
                     W_in_snk, b_in_snk, a1_in_snk, a2_in_snk,
                     seA, skA, N);

  // ---- layers 2..L ----
  for (int i = 0; i < L - 1; ++i){
    hipLaunchKernelGGL(k_linear, dim3(gN32), dim3(TB), 0, stream,
                       seA, skA, W_src + (size_t)i * 1024, W_snk + (size_t)i * 1024,
                       a1_src + i * 32, a2_src + i * 32, a1_snk + i * 32, a2_snk + i * 32,
                       hS, hK, a1Sv, a2Sv, a1Kv, a2Kv, N);
    hipLaunchKernelGGL(k_gat_agg, dim3(gNode8, 2), dim3(TB), 0, stream,
                       rsS, colS, hS, a1Sv, a2Sv, b_src + i * 32, seA,
                       rsK, colK, hK, a1Kv, a2Kv, b_snk + i * 32, skA, N);
  }

  // ---- heads ----
  hipLaunchKernelGGL(k_head0, dim3(gN64), dim3(TB), 0, stream,
                     seA, skA, W_o_src, b_o_src, W_o_snk, b_o_snk, comb, outp, N);
  hipLaunchKernelGGL(k_head1, dim3(gNode4), dim3(TB), 0, stream,
                     rsS, colS, rsK, colK, comb, x, W_d1, b_d1, outp, N);
}